// Round 11
// baseline (134.724 us; speedup 1.0000x reference)
//
#include <hip/hip_runtime.h>
#include <hip/hip_bf16.h>

#define NFFT   4194304
#define NMODES 2
#define NTAPS  101
#define NVALID (NFFT - NTAPS + 1)   // 4194204
#define N0     (NTAPS / 2)          // 50

constexpr int BLOCK = 256;
constexpr int CPT   = 8;                    // consecutive outputs per thread
constexpr int TILE  = BLOCK * CPT;          // 2048 outputs per block
constexpr int WIN   = TILE + NTAPS - 1;     // 2148 staged P samples
constexpr int PITCH = 269;                  // rows per phase (max row touched = 268)

static __device__ __forceinline__ unsigned short f2bf(float x) {
    __hip_bfloat16 h = __float2bfloat16(x);
    return *reinterpret_cast<unsigned short*>(&h);
}
static __device__ __forceinline__ unsigned pk(float e0, float e1) {
    return (unsigned)f2bf(e0) | ((unsigned)f2bf(e1) << 16);
}

// 8 outputs/thread FIR step for one tap; P_i = window element (tap + i)
#define FIRTAP(WT, P0,P1,P2,P3,P4,P5,P6,P7)                                          \
    acc[0][0]=fmaf(P0.x,WT.x,fmaf(P0.y,WT.z,acc[0][0]));                             \
    acc[0][1]=fmaf(P0.x,WT.y,fmaf(P0.y,WT.w,acc[0][1]));                             \
    acc[1][0]=fmaf(P1.x,WT.x,fmaf(P1.y,WT.z,acc[1][0]));                             \
    acc[1][1]=fmaf(P1.x,WT.y,fmaf(P1.y,WT.w,acc[1][1]));                             \
    acc[2][0]=fmaf(P2.x,WT.x,fmaf(P2.y,WT.z,acc[2][0]));                             \
    acc[2][1]=fmaf(P2.x,WT.y,fmaf(P2.y,WT.w,acc[2][1]));                             \
    acc[3][0]=fmaf(P3.x,WT.x,fmaf(P3.y,WT.z,acc[3][0]));                             \
    acc[3][1]=fmaf(P3.x,WT.y,fmaf(P3.y,WT.w,acc[3][1]));                             \
    acc[4][0]=fmaf(P4.x,WT.x,fmaf(P4.y,WT.z,acc[4][0]));                             \
    acc[4][1]=fmaf(P4.x,WT.y,fmaf(P4.y,WT.w,acc[4][1]));                             \
    acc[5][0]=fmaf(P5.x,WT.x,fmaf(P5.y,WT.z,acc[5][0]));                             \
    acc[5][1]=fmaf(P5.x,WT.y,fmaf(P5.y,WT.w,acc[5][1]));                             \
    acc[6][0]=fmaf(P6.x,WT.x,fmaf(P6.y,WT.z,acc[6][0]));                             \
    acc[6][1]=fmaf(P6.x,WT.y,fmaf(P6.y,WT.w,acc[6][1]));                             \
    acc[7][0]=fmaf(P7.x,WT.x,fmaf(P7.y,WT.z,acc[7][0]));                             \
    acc[7][1]=fmaf(P7.x,WT.y,fmaf(P7.y,WT.w,acc[7][1]));

// one tap of a 16-tap chunk: prefetch elem 16K+J+15 into named slot SNEW
// (dead elem 16K+J-1), then FMA over named slots J..J+7 (mod 16).
#define STEP(J, SNEW, PH, RADD, P0,P1,P2,P3,P4,P5,P6,P7)                             \
    SNEW = Pl[(PH)*PITCH + krow + (RADD)];                                           \
    { const float4 wt = W4[16*K + (J)]; FIRTAP(wt, P0,P1,P2,P3,P4,P5,P6,P7) }

#define TAILTAP(T, P0,P1,P2,P3,P4,P5,P6,P7)                                          \
    { const float4 wt = W4[T]; FIRTAP(wt, P0,P1,P2,P3,P4,P5,P6,P7) }

__global__ __launch_bounds__(BLOCK, 4) void nl_kernel(
    const float* __restrict__ xa,   // d_in[0] big stream (A)
    const float* __restrict__ xb,   // d_in[1] big stream (B)
    const float* __restrict__ W,  const float* __restrict__ b,
    const float* __restrict__ power, unsigned* __restrict__ out)
{
    // P element e (e = tid*8 + m) lives at Pl[(m&7)*PITCH + tid + (m>>3)]
    __shared__ float2 Pl[CPT * PITCH];

    const int tid = threadIdx.x;
    const int tile_start = blockIdx.x * TILE;

    // ---- stage P = A^2 + B^2 into phase-swizzled LDS ----
    const float2* __restrict__ xa2 = reinterpret_cast<const float2*>(xa);
    const float2* __restrict__ xb2 = reinterpret_cast<const float2*>(xb);
    for (int idx = tid; idx < WIN; idx += BLOCK) {
        const int g = tile_start + idx;
        float2 p = make_float2(0.f, 0.f);
        if (g < NFFT) {
            const float2 a = xa2[g];
            const float2 c = xb2[g];
            p.x = a.x * a.x + c.x * c.x;
            p.y = a.y * a.y + c.y * c.y;
        }
        Pl[(idx & 7) * PITCH + (idx >> 3)] = p;
    }
    __syncthreads();

    float acc[CPT][2];
    const float b0 = b[0], b1 = b[1];
    #pragma unroll
    for (int c = 0; c < CPT; ++c) { acc[c][0] = b0; acc[c][1] = b1; }

    const float4* __restrict__ W4 = reinterpret_cast<const float4*>(W);

    // ---- 16-slot ring as NAMED registers (spill-proof). Slot m&15 == element m.
    float2 w0,w1,w2,w3,w4,w5,w6,w7,w8,w9,w10,w11,w12,w13,w14,w15;
    w0  = Pl[0*PITCH + tid];     w1  = Pl[1*PITCH + tid];
    w2  = Pl[2*PITCH + tid];     w3  = Pl[3*PITCH + tid];
    w4  = Pl[4*PITCH + tid];     w5  = Pl[5*PITCH + tid];
    w6  = Pl[6*PITCH + tid];     w7  = Pl[7*PITCH + tid];
    w8  = Pl[0*PITCH + tid + 1]; w9  = Pl[1*PITCH + tid + 1];
    w10 = Pl[2*PITCH + tid + 1]; w11 = Pl[3*PITCH + tid + 1];
    w12 = Pl[4*PITCH + tid + 1]; w13 = Pl[5*PITCH + tid + 1];
    w14 = Pl[6*PITCH + tid + 1];
    w15 = make_float2(0.f, 0.f);  // written at j=0 before first read (j=8)

    for (int K = 0; K < 6; ++K) {             // taps 16K .. 16K+15  (0..95)
        const int krow = tid + 2 * K;
        STEP( 0, w15, 7, 1,  w0,w1,w2,w3,w4,w5,w6,w7)
        STEP( 1, w0,  0, 2,  w1,w2,w3,w4,w5,w6,w7,w8)
        STEP( 2, w1,  1, 2,  w2,w3,w4,w5,w6,w7,w8,w9)
        STEP( 3, w2,  2, 2,  w3,w4,w5,w6,w7,w8,w9,w10)
        STEP( 4, w3,  3, 2,  w4,w5,w6,w7,w8,w9,w10,w11)
        STEP( 5, w4,  4, 2,  w5,w6,w7,w8,w9,w10,w11,w12)
        STEP( 6, w5,  5, 2,  w6,w7,w8,w9,w10,w11,w12,w13)
        STEP( 7, w6,  6, 2,  w7,w8,w9,w10,w11,w12,w13,w14)
        STEP( 8, w7,  7, 2,  w8,w9,w10,w11,w12,w13,w14,w15)
        STEP( 9, w8,  0, 3,  w9,w10,w11,w12,w13,w14,w15,w0)
        STEP(10, w9,  1, 3,  w10,w11,w12,w13,w14,w15,w0,w1)
        STEP(11, w10, 2, 3,  w11,w12,w13,w14,w15,w0,w1,w2)
        STEP(12, w11, 3, 3,  w12,w13,w14,w15,w0,w1,w2,w3)
        STEP(13, w12, 4, 3,  w13,w14,w15,w0,w1,w2,w3,w4)
        STEP(14, w13, 5, 3,  w14,w15,w0,w1,w2,w3,w4,w5)
        STEP(15, w14, 6, 3,  w15,w0,w1,w2,w3,w4,w5,w6)
    }
    // tail taps 96..100; after K=5, slot s holds element 96+s (s=0..14)
    TAILTAP(96, w0,w1,w2,w3,w4,w5,w6,w7)
    TAILTAP(97, w1,w2,w3,w4,w5,w6,w7,w8)
    TAILTAP(98, w2,w3,w4,w5,w6,w7,w8,w9)
    TAILTAP(99, w3,w4,w5,w6,w7,w8,w9,w10)
    TAILTAP(100, w4,w5,w6,w7,w8,w9,w10,w11)

    // ---- phase rotation + bf16 pack (verified R7 form) ----
    // elem0 = B*cos - A*sin ; elem1 = A*cos + B*sin, theta = acc*coef
    const float coef = 0.066268f * exp10f(power[0] * 0.1f);
    const int base = tile_start + tid * CPT;

    const float4* __restrict__ xa4 = reinterpret_cast<const float4*>(xa); // 2 samples
    const float4* __restrict__ xb4 = reinterpret_cast<const float4*>(xb);
    uint4* __restrict__ out4 = reinterpret_cast<uint4*>(out);             // 2 samples

    #pragma unroll
    for (int cc = 0; cc < 4; ++cc) {
        const int n0 = base + 2 * cc;              // even
        const int c0 = 2 * cc;
        if (n0 + 1 < NVALID) {                     // fast path: both samples valid
            const float4 A = xa4[(n0 + N0) >> 1];  // {s0.m0, s0.m1, s1.m0, s1.m1}
            const float4 B = xb4[(n0 + N0) >> 1];
            float s00, c00, s01, c01, s10, c10, s11, c11;
            __sincosf(acc[c0][0]     * coef, &s00, &c00);
            __sincosf(acc[c0][1]     * coef, &s01, &c01);
            __sincosf(acc[c0 + 1][0] * coef, &s10, &c10);
            __sincosf(acc[c0 + 1][1] * coef, &s11, &c11);
            uint4 o;
            o.x = pk(B.x * c00 - A.x * s00, A.x * c00 + B.x * s00); // s0 mode0
            o.y = pk(B.y * c01 - A.y * s01, A.y * c01 + B.y * s01); // s0 mode1
            o.z = pk(B.z * c10 - A.z * s10, A.z * c10 + B.z * s10); // s1 mode0
            o.w = pk(B.w * c11 - A.w * s11, A.w * c11 + B.w * s11); // s1 mode1
            out4[n0 >> 1] = o;
        } else {
            #pragma unroll
            for (int dc = 0; dc < 2; ++dc) {
                const int n = n0 + dc;
                if (n < NVALID) {
                    const float2 A = xa2[n + N0];
                    const float2 B = xb2[n + N0];
                    float s0, c0s, s1, c1s;
                    __sincosf(acc[c0 + dc][0] * coef, &s0, &c0s);
                    __sincosf(acc[c0 + dc][1] * coef, &s1, &c1s);
                    uint2 o;
                    o.x = pk(B.x * c0s - A.x * s0, A.x * c0s + B.x * s0);
                    o.y = pk(B.y * c1s - A.y * s1, A.y * c1s + B.y * s1);
                    reinterpret_cast<uint2*>(out)[n] = o;
                }
            }
        }
    }
}

extern "C" void kernel_launch(void* const* d_in, const int* in_sizes, int n_in,
                              void* d_out, int out_size, void* d_ws, size_t ws_size,
                              hipStream_t stream) {
    // Bind by size (robust): big arrays = x streams, 404 = W, 2 = b, 1 = power.
    const float* big[2] = {nullptr, nullptr};
    const float* W = nullptr; const float* b = nullptr; const float* power = nullptr;
    int nbig = 0;
    for (int i = 0; i < n_in; ++i) {
        const float* p = (const float*)d_in[i];
        const int sz = in_sizes[i];
        if (sz == NFFT * NMODES)       { if (nbig < 2) big[nbig++] = p; }
        else if (sz == NTAPS * NMODES * NMODES) { W = p; }
        else if (sz == NMODES)         { b = p; }
        else if (sz == 1)              { power = p; }
    }

    unsigned* out = (unsigned*)d_out;
    const int grid = (NVALID + TILE - 1) / TILE;  // 2048 blocks
    nl_kernel<<<grid, BLOCK, 0, stream>>>(big[0], big[1], W, b, power, out);
}